// Round 2
// baseline (1864.809 us; speedup 1.0000x reference)
//
#include <hip/hip_runtime.h>
#include <hip/hip_bf16.h>
#include <math.h>

#define B 2

__device__ __forceinline__ float toF(float x) { return x; }
__device__ __forceinline__ float toF(__hip_bfloat16 x) { return __bfloat162float(x); }
__device__ __forceinline__ void stF(float* p, float v) { *p = v; }
__device__ __forceinline__ void stF(__hip_bfloat16* p, float v) { *p = __float2bfloat16(v); }

// ---------------- dtype probe: flag=1 if buffer is bf16, 0 if f32 ----------------
// True bf16 (N(0,1) data): ~all halfwords have exponent near 127.
// f32 viewed as bf16: even halfwords = low mantissa bits -> random exponents (~24% sane).
__global__ void probe_kernel(const unsigned short* __restrict__ x, int* __restrict__ flag) {
  if (threadIdx.x == 0 && blockIdx.x == 0) {
    int sane = 0;
    for (int i = 0; i < 512; ++i) {
      int e = (x[i] >> 7) & 0xFF;
      if (e >= 97 && e <= 157) ++sane;
    }
    flag[0] = (sane >= 480) ? 1 : 0;
  }
}

// ---------------- conv5: 3x3 conv (pad 1) on c4 (B,2048,16,16) -> split-K partials ----
template <typename TP>
__global__ __launch_bounds__(256) void conv5_kernel(
    const TP* __restrict__ c4, const TP* __restrict__ w,
    float* __restrict__ part, const int* __restrict__ flag, int want)
{
  if (flag[0] != want) return;
  const int ks  = blockIdx.x;
  const int oc0 = blockIdx.y * 4;
  const int n   = blockIdx.z;
  const int tid = threadIdx.x;
  const int x = tid & 15, y = tid >> 4;

  __shared__ float xs[8][18][18];
  __shared__ float wt[4][8][9];

  float* xsf = &xs[0][0][0];
  for (int i = tid; i < 8 * 18 * 18; i += 256) xsf[i] = 0.f;

  float acc[4] = {0.f, 0.f, 0.f, 0.f};
  __syncthreads();

  for (int cc = 0; cc < 64; ++cc) {
    const int c0 = ks * 512 + cc * 8;
#pragma unroll
    for (int i = 0; i < 8; ++i)
      xs[i][1 + y][1 + x] = toF(c4[(((size_t)n * 2048 + c0 + i) << 8) + tid]);
    for (int e = tid; e < 288; e += 256) {
      int o = e / 72, r = e % 72, i = r / 9, kk = r % 9;
      wt[o][i][kk] = toF(w[((size_t)(oc0 + o) * 2048 + (c0 + i)) * 9 + kk]);
    }
    __syncthreads();
#pragma unroll
    for (int i = 0; i < 8; ++i) {
      float t0 = xs[i][y    ][x], t1 = xs[i][y    ][x + 1], t2 = xs[i][y    ][x + 2];
      float t3 = xs[i][y + 1][x], t4 = xs[i][y + 1][x + 1], t5 = xs[i][y + 1][x + 2];
      float t6 = xs[i][y + 2][x], t7 = xs[i][y + 2][x + 1], t8 = xs[i][y + 2][x + 2];
#pragma unroll
      for (int o = 0; o < 4; ++o) {
        acc[o] = fmaf(t0, wt[o][i][0], acc[o]);
        acc[o] = fmaf(t1, wt[o][i][1], acc[o]);
        acc[o] = fmaf(t2, wt[o][i][2], acc[o]);
        acc[o] = fmaf(t3, wt[o][i][3], acc[o]);
        acc[o] = fmaf(t4, wt[o][i][4], acc[o]);
        acc[o] = fmaf(t5, wt[o][i][5], acc[o]);
        acc[o] = fmaf(t6, wt[o][i][6], acc[o]);
        acc[o] = fmaf(t7, wt[o][i][7], acc[o]);
        acc[o] = fmaf(t8, wt[o][i][8], acc[o]);
      }
    }
    __syncthreads();
  }
#pragma unroll
  for (int o = 0; o < 4; ++o)
    part[(size_t)ks * 262144 + ((size_t)n * 512 + oc0 + o) * 256 + tid] = acc[o];
}

template <typename TP>
__global__ __launch_bounds__(256) void finalize5_kernel(
    const float* __restrict__ part, const TP* __restrict__ bn,
    float* __restrict__ t5, const int* __restrict__ flag, int want)
{
  if (flag[0] != want) return;
  int idx = blockIdx.x * 256 + threadIdx.x;   // 262144 total
  int oc = (idx >> 8) & 511;
  float s = part[idx] + part[idx + 262144] + part[idx + 2 * 262144] + part[idx + 3 * 262144];
  float g = toF(bn[oc]), b = toF(bn[512 + oc]), m = toF(bn[1024 + oc]), v = toF(bn[1536 + oc]);
  float sc = g * rsqrtf(v + 1e-5f);
  float val = s * sc + (b - m * sc);
  t5[idx] = fmaxf(val, 0.f);
}

// ---------------- generic 1x1 conv (+optional BN) ----------------
template <typename TX, typename TP>
__global__ __launch_bounds__(256) void conv1x1_kernel(
    const TX* __restrict__ X, const TP* __restrict__ Wm,
    const TP* __restrict__ bn,
    float* __restrict__ Y, int C, int O, int S,
    const int* __restrict__ flag, int want)
{
  if (flag[0] != want) return;
  const int tid = threadIdx.x;
  const int sg = tid & 15, og = tid >> 4;
  const int s0 = blockIdx.x * 64;
  const int o0 = blockIdx.y * 64;
  const int n  = blockIdx.z;

  __shared__ float xs[16][64];
  __shared__ float wsT[16][68];

  float acc[4][4];
#pragma unroll
  for (int i = 0; i < 4; ++i)
#pragma unroll
    for (int j = 0; j < 4; ++j) acc[i][j] = 0.f;

  for (int c0 = 0; c0 < C; c0 += 16) {
#pragma unroll
    for (int r = 0; r < 4; ++r) {
      int e = tid + r * 256, cc = e >> 6, ssv = e & 63;
      xs[cc][ssv] = toF(X[((size_t)n * C + c0 + cc) * S + s0 + ssv]);
    }
#pragma unroll
    for (int r = 0; r < 4; ++r) {
      int e = tid + r * 256, oo = e >> 4, cc = e & 15;
      int o = o0 + oo;
      wsT[cc][oo] = (o < O) ? toF(Wm[(size_t)o * C + c0 + cc]) : 0.f;
    }
    __syncthreads();
#pragma unroll
    for (int c = 0; c < 16; ++c) {
      const float4 xv = *(const float4*)&xs[c][sg * 4];
      const float4 wv = *(const float4*)&wsT[c][og * 4];
      acc[0][0] = fmaf(wv.x, xv.x, acc[0][0]);
      acc[0][1] = fmaf(wv.x, xv.y, acc[0][1]);
      acc[0][2] = fmaf(wv.x, xv.z, acc[0][2]);
      acc[0][3] = fmaf(wv.x, xv.w, acc[0][3]);
      acc[1][0] = fmaf(wv.y, xv.x, acc[1][0]);
      acc[1][1] = fmaf(wv.y, xv.y, acc[1][1]);
      acc[1][2] = fmaf(wv.y, xv.z, acc[1][2]);
      acc[1][3] = fmaf(wv.y, xv.w, acc[1][3]);
      acc[2][0] = fmaf(wv.z, xv.x, acc[2][0]);
      acc[2][1] = fmaf(wv.z, xv.y, acc[2][1]);
      acc[2][2] = fmaf(wv.z, xv.z, acc[2][2]);
      acc[2][3] = fmaf(wv.z, xv.w, acc[2][3]);
      acc[3][0] = fmaf(wv.w, xv.x, acc[3][0]);
      acc[3][1] = fmaf(wv.w, xv.y, acc[3][1]);
      acc[3][2] = fmaf(wv.w, xv.z, acc[3][2]);
      acc[3][3] = fmaf(wv.w, xv.w, acc[3][3]);
    }
    __syncthreads();
  }

#pragma unroll
  for (int i = 0; i < 4; ++i) {
    int o = o0 + og * 4 + i;
    if (o < O) {
      float sc = 1.f, sh = 0.f;
      if (bn) {
        float g = toF(bn[o]), bb = toF(bn[O + o]), m = toF(bn[2 * O + o]), v = toF(bn[3 * O + o]);
        sc = g * rsqrtf(v + 1e-5f);
        sh = bb - m * sc;
      }
      float4 r;
      r.x = acc[i][0] * sc + sh;
      r.y = acc[i][1] * sc + sh;
      r.z = acc[i][2] * sc + sh;
      r.w = acc[i][3] * sc + sh;
      *(float4*)(Y + ((size_t)n * O + o) * S + s0 + sg * 4) = r;
    }
  }
}

// ---------------- bilinear 2x upsample, align_corners=True (fp32 intermediates) ------
__global__ __launch_bounds__(256) void upsample2x_kernel(
    const float* __restrict__ in, float* __restrict__ out,
    int h, int w, int total)
{
  int idx = blockIdx.x * 256 + threadIdx.x;
  if (idx >= total) return;
  const int Wd = 2 * w, Hd = 2 * h;
  int xo = idx % Wd;
  int t  = idx / Wd;
  int yo = t % Hd;
  int pl = t / Hd;
  const float rh = (float)(h - 1) / (float)(Hd - 1);
  const float rw = (float)(w - 1) / (float)(Wd - 1);
  float fy = yo * rh, fx = xo * rw;
  int y0 = (int)fy; if (y0 > h - 1) y0 = h - 1;
  int x0 = (int)fx; if (x0 > w - 1) x0 = w - 1;
  int y1 = min(y0 + 1, h - 1), x1 = min(x0 + 1, w - 1);
  float wy = fy - y0, wx = fx - x0;
  const float* p = in + (size_t)pl * h * w;
  float v00 = p[y0 * w + x0], v01 = p[y0 * w + x1];
  float v10 = p[y1 * w + x0], v11 = p[y1 * w + x1];
  out[idx] = (v00 * (1.f - wy) + v10 * wy) * (1.f - wx) +
             (v01 * (1.f - wy) + v11 * wy) * wx;
}

// ---------------- 9-tap local attention logits + softmax ----------------
// zero-padded taps contribute LOGIT 0 and stay in the softmax denominator.
__global__ __launch_bounds__(256) void att_kernel(
    const float* __restrict__ q, const float* __restrict__ k,
    float* __restrict__ att, int kd, int H, int Wd, int total)
{
  int idx = blockIdx.x * 256 + threadIdx.x;
  if (idx >= total) return;
  const int S = H * Wd;
  int p = idx % S, n = idx / S;
  int x = p % Wd, y = p / Wd;
  int off[9]; bool ok[9];
#pragma unroll
  for (int j = 0; j < 9; ++j) {
    int dy = (j / 3) * 2 - 2, dx = (j % 3) * 2 - 2;
    int yy = y + dy, xx = x + dx;
    ok[j] = (yy >= 0 && yy < H && xx >= 0 && xx < Wd);
    off[j] = yy * Wd + xx;
  }
  float dot[9] = {0.f,0.f,0.f,0.f,0.f,0.f,0.f,0.f,0.f};
  const float* qp = q + (size_t)n * kd * S + p;
  const float* kp = k + (size_t)n * kd * S;
  for (int c = 0; c < kd; ++c) {
    float qv = qp[(size_t)c * S];
    const float* kc = kp + (size_t)c * S;
#pragma unroll
    for (int j = 0; j < 9; ++j)
      if (ok[j]) dot[j] = fmaf(qv, kc[off[j]], dot[j]);
  }
  float m = dot[0];
#pragma unroll
  for (int j = 1; j < 9; ++j) m = fmaxf(m, dot[j]);
  float e[9], ssum = 0.f;
#pragma unroll
  for (int j = 0; j < 9; ++j) { e[j] = __expf(dot[j] - m); ssum += e[j]; }
  float inv = 1.f / ssum;
#pragma unroll
  for (int j = 0; j < 9; ++j)
    att[((size_t)n * 9 + j) * S + p] = e[j] * inv;
}

// -------- fused: out[n,c,p] = sum_j att[n,j,p] * bilerp(prev[n,c], tap_j(p)) --------
// prev is at (h2,w2); taps are at hi-res (H,W); align_corners=True mapping.
__global__ __launch_bounds__(256) void apply_up_kernel(
    const float* __restrict__ att, const float* __restrict__ prev,
    float* __restrict__ out, int C, int H, int Wd, int h2, int w2, int total)
{
  int idx = blockIdx.x * 256 + threadIdx.x;
  if (idx >= total) return;
  const int S = H * Wd;
  int p = idx % S;
  int t = idx / S;
  int c = t % C, n = t / C;
  int x = p % Wd, y = p / Wd;
  const float rh = (float)(h2 - 1) / (float)(H - 1);
  const float rw = (float)(w2 - 1) / (float)(Wd - 1);
  const float* ap = att + (size_t)n * 9 * S + p;
  const float* pc = prev + ((size_t)n * C + c) * h2 * w2;
  float v = 0.f;
#pragma unroll
  for (int j = 0; j < 9; ++j) {
    int dy = (j / 3) * 2 - 2, dx = (j % 3) * 2 - 2;
    int yy = y + dy, xx = x + dx;
    if (yy >= 0 && yy < H && xx >= 0 && xx < Wd) {
      float fy = yy * rh, fx = xx * rw;
      int y0 = (int)fy; if (y0 > h2 - 1) y0 = h2 - 1;
      int x0 = (int)fx; if (x0 > w2 - 1) x0 = w2 - 1;
      int y1 = min(y0 + 1, h2 - 1), x1 = min(x0 + 1, w2 - 1);
      float wy = fy - y0, wx = fx - x0;
      float v00 = pc[y0 * w2 + x0], v01 = pc[y0 * w2 + x1];
      float v10 = pc[y1 * w2 + x0], v11 = pc[y1 * w2 + x1];
      float b = (v00 * (1.f - wy) + v10 * wy) * (1.f - wx) +
                (v01 * (1.f - wy) + v11 * wy) * wx;
      v = fmaf(ap[(size_t)j * S], b, v);
    }
  }
  out[idx] = v;
}

// -------- final: d_out[n,o,p] = b[o] + sum_j att2[j,p] * bilerp(v6s[n,o], tap_j(p)) --
template <typename TP>
__global__ __launch_bounds__(256) void final_kernel(
    const float* __restrict__ att, const float* __restrict__ v6s,
    const TP* __restrict__ bias, TP* __restrict__ out, int total,
    const int* __restrict__ flag, int want)
{
  if (flag[0] != want) return;
  int idx = blockIdx.x * 256 + threadIdx.x;
  if (idx >= total) return;
  const int H = 128, Wd = 128, h2 = 64, w2 = 64;
  const int S = H * Wd;
  int p = idx % S;
  int t = idx / S;
  int o = t % 19, n = t / 19;
  int x = p % Wd, y = p / Wd;
  const float rh = (float)(h2 - 1) / (float)(H - 1);
  const float rw = (float)(w2 - 1) / (float)(Wd - 1);
  const float* ap = att + (size_t)n * 9 * S + p;
  const float* pc = v6s + ((size_t)n * 19 + o) * h2 * w2;
  float v = toF(bias[o]);
#pragma unroll
  for (int j = 0; j < 9; ++j) {
    int dy = (j / 3) * 2 - 2, dx = (j % 3) * 2 - 2;
    int yy = y + dy, xx = x + dx;
    if (yy >= 0 && yy < H && xx >= 0 && xx < Wd) {
      float fy = yy * rh, fx = xx * rw;
      int y0 = (int)fy; if (y0 > h2 - 1) y0 = h2 - 1;
      int x0 = (int)fx; if (x0 > w2 - 1) x0 = w2 - 1;
      int y1 = min(y0 + 1, h2 - 1), x1 = min(x0 + 1, w2 - 1);
      float wy = fy - y0, wx = fx - x0;
      float v00 = pc[y0 * w2 + x0], v01 = pc[y0 * w2 + x1];
      float v10 = pc[y1 * w2 + x0], v11 = pc[y1 * w2 + x1];
      float b = (v00 * (1.f - wy) + v10 * wy) * (1.f - wx) +
                (v01 * (1.f - wy) + v11 * wy) * wx;
      v = fmaf(ap[(size_t)j * S], b, v);
    }
  }
  stF(&out[idx], v);
}

typedef __hip_bfloat16 bf16;

extern "C" void kernel_launch(void* const* d_in, const int* in_sizes, int n_in,
                              void* d_out, int out_size, void* d_ws, size_t ws_size,
                              hipStream_t stream) {
  (void)in_sizes; (void)n_in; (void)out_size; (void)ws_size;

  float* ws = (float*)d_ws;   // disjoint fp32 workspace, 13,584,385 floats = 51.8 MiB
  float* p5   = ws + 0;          // 1,048,576
  float* t5   = ws + 1048576;    //   262,144
  float* q4   = ws + 1310720;    //   262,144
  float* k4s  = ws + 1572864;    //    65,536
  float* k4   = ws + 1638400;    //   262,144
  float* att4 = ws + 1900544;    //    18,432
  float* o4   = ws + 1918976;    // 1,048,576
  float* q3   = ws + 2967552;    //   524,288
  float* k3s  = ws + 3491840;    //   131,072
  float* k3   = ws + 3622912;    //   524,288
  float* att3 = ws + 4147200;    //    73,728
  float* o3   = ws + 4220928;    // 4,194,304
  float* v6s  = ws + 8415232;    //   155,648
  float* q2   = ws + 8570880;    // 2,097,152
  float* k2s  = ws + 10668032;   //   524,288
  float* k2   = ws + 11192320;   // 2,097,152
  float* att2 = ws + 13289472;   //   294,912
  int*   flag = (int*)(ws + 13584384);

  probe_kernel<<<1, 64, 0, stream>>>((const unsigned short*)d_in[0], flag);

  // Launch both dtype variants; the probe flag selects which one executes.
#define DUAL(CALL_BF, CALL_F32) do { CALL_BF; CALL_F32; } while (0)

  // ---- conv5 + BN + ReLU ----
  DUAL(
    (conv5_kernel<bf16><<<dim3(4, 128, B), 256, 0, stream>>>((const bf16*)d_in[3], (const bf16*)d_in[7], p5, flag, 1)),
    (conv5_kernel<float><<<dim3(4, 128, B), 256, 0, stream>>>((const float*)d_in[3], (const float*)d_in[7], p5, flag, 0)));
  DUAL(
    (finalize5_kernel<bf16><<<1024, 256, 0, stream>>>(p5, (const bf16*)d_in[8], t5, flag, 1)),
    (finalize5_kernel<float><<<1024, 256, 0, stream>>>(p5, (const float*)d_in[8], t5, flag, 0)));

  // ---- localUp stage 4 (H=32, kd=128): c_hi=c3, c_lo=c40, prev=t5 ----
  DUAL(
    (conv1x1_kernel<bf16, bf16><<<dim3(16, 2, B), 256, 0, stream>>>((const bf16*)d_in[2], (const bf16*)d_in[11], (const bf16*)d_in[12], q4, 1024, 128, 1024, flag, 1)),
    (conv1x1_kernel<float, float><<<dim3(16, 2, B), 256, 0, stream>>>((const float*)d_in[2], (const float*)d_in[11], (const float*)d_in[12], q4, 1024, 128, 1024, flag, 0)));
  DUAL(
    (conv1x1_kernel<bf16, bf16><<<dim3(4, 2, B), 256, 0, stream>>>((const bf16*)d_in[6], (const bf16*)d_in[13], (const bf16*)d_in[14], k4s, 2048, 128, 256, flag, 1)),
    (conv1x1_kernel<float, float><<<dim3(4, 2, B), 256, 0, stream>>>((const float*)d_in[6], (const float*)d_in[13], (const float*)d_in[14], k4s, 2048, 128, 256, flag, 0)));
  upsample2x_kernel<<<1024, 256, 0, stream>>>(k4s, k4, 16, 16, B * 128 * 1024);
  att_kernel<<<8, 256, 0, stream>>>(q4, k4, att4, 128, 32, 32, B * 1024);
  apply_up_kernel<<<4096, 256, 0, stream>>>(att4, t5, o4, 512, 32, 32, 16, 16, B * 512 * 1024);

  // ---- localUp stage 3 (H=64, kd=64): c_hi=c2, c_lo=c30, prev=o4 ----
  DUAL(
    (conv1x1_kernel<bf16, bf16><<<dim3(64, 1, B), 256, 0, stream>>>((const bf16*)d_in[1], (const bf16*)d_in[15], (const bf16*)d_in[16], q3, 512, 64, 4096, flag, 1)),
    (conv1x1_kernel<float, float><<<dim3(64, 1, B), 256, 0, stream>>>((const float*)d_in[1], (const float*)d_in[15], (const float*)d_in[16], q3, 512, 64, 4096, flag, 0)));
  DUAL(
    (conv1x1_kernel<bf16, bf16><<<dim3(16, 1, B), 256, 0, stream>>>((const bf16*)d_in[5], (const bf16*)d_in[17], (const bf16*)d_in[18], k3s, 1024, 64, 1024, flag, 1)),
    (conv1x1_kernel<float, float><<<dim3(16, 1, B), 256, 0, stream>>>((const float*)d_in[5], (const float*)d_in[17], (const float*)d_in[18], k3s, 1024, 64, 1024, flag, 0)));
  upsample2x_kernel<<<2048, 256, 0, stream>>>(k3s, k3, 32, 32, B * 64 * 4096);
  att_kernel<<<32, 256, 0, stream>>>(q3, k3, att3, 64, 64, 64, B * 4096);
  apply_up_kernel<<<16384, 256, 0, stream>>>(att3, o4, o3, 512, 64, 64, 32, 32, B * 512 * 4096);

  // ---- localUp stage 2 (H=128, kd=64): c_hi=c1, c_lo=c2, prev=o3; conv6 commuted ----
  DUAL(
    (conv1x1_kernel<bf16, bf16><<<dim3(256, 1, B), 256, 0, stream>>>((const bf16*)d_in[0], (const bf16*)d_in[19], (const bf16*)d_in[20], q2, 256, 64, 16384, flag, 1)),
    (conv1x1_kernel<float, float><<<dim3(256, 1, B), 256, 0, stream>>>((const float*)d_in[0], (const float*)d_in[19], (const float*)d_in[20], q2, 256, 64, 16384, flag, 0)));
  DUAL(
    (conv1x1_kernel<bf16, bf16><<<dim3(64, 1, B), 256, 0, stream>>>((const bf16*)d_in[1], (const bf16*)d_in[21], (const bf16*)d_in[22], k2s, 512, 64, 4096, flag, 1)),
    (conv1x1_kernel<float, float><<<dim3(64, 1, B), 256, 0, stream>>>((const float*)d_in[1], (const float*)d_in[21], (const float*)d_in[22], k2s, 512, 64, 4096, flag, 0)));
  upsample2x_kernel<<<8192, 256, 0, stream>>>(k2s, k2, 64, 64, B * 64 * 16384);
  att_kernel<<<128, 256, 0, stream>>>(q2, k2, att2, 64, 128, 128, B * 16384);
  // v6s = conv6(o3) at 64x64 (conv6 commutes with upsample AND the 9-tap gather)
  DUAL(
    (conv1x1_kernel<float, bf16><<<dim3(64, 1, B), 256, 0, stream>>>(o3, (const bf16*)d_in[9], (const bf16*)nullptr, v6s, 512, 19, 4096, flag, 1)),
    (conv1x1_kernel<float, float><<<dim3(64, 1, B), 256, 0, stream>>>(o3, (const float*)d_in[9], (const float*)nullptr, v6s, 512, 19, 4096, flag, 0)));
  DUAL(
    (final_kernel<bf16><<<2432, 256, 0, stream>>>(att2, v6s, (const bf16*)d_in[10], (bf16*)d_out, B * 19 * 16384, flag, 1)),
    (final_kernel<float><<<2432, 256, 0, stream>>>(att2, v6s, (const float*)d_in[10], (float*)d_out, B * 19 * 16384, flag, 0)));
}